// Round 5
// baseline (298.716 us; speedup 1.0000x reference)
//
#include <hip/hip_runtime.h>
#include <hip/hip_bf16.h>

#define BATCH 32
#define SEQ   2048
#define DIM   1024

typedef __attribute__((ext_vector_type(4))) float f32x4;
typedef __attribute__((ext_vector_type(8))) short short8;

static __device__ __forceinline__ ushort f2bf(float x) {
    __hip_bfloat16 h = __float2bfloat16(x);
    union { __hip_bfloat16 h; ushort u; } cv; cv.h = h;
    return cv.u;
}

// ---------------- k0a: Wh f32 -> bf16, packed in MFMA B-fragment order ----------------
// whbp[((eb*32 + kb)*64 + lane)*8 + j] = bf16( Wh[eb*16 + (lane&15)][kb*32 + (lane>>4)*8 + j] )
__global__ __launch_bounds__(256) void kWhPack(const float* __restrict__ Wh,
                                               ushort* __restrict__ whbp) {
    int g = blockIdx.x * 256 + threadIdx.x;      // 131072 total
    int l  = g & 63;
    int kb = (g >> 6) & 31;
    int eb = g >> 11;
    int e  = eb * 16 + (l & 15);
    int k0 = kb * 32 + (l >> 4) * 8;
    const float* src = Wh + (size_t)e * DIM + k0;
    float4 a = *(const float4*)src;
    float4 b = *(const float4*)(src + 4);
    union { ushort us[8]; uint4 u4; } pk;
    pk.us[0] = f2bf(a.x); pk.us[1] = f2bf(a.y); pk.us[2] = f2bf(a.z); pk.us[3] = f2bf(a.w);
    pk.us[4] = f2bf(b.x); pk.us[5] = f2bf(b.y); pk.us[6] = f2bf(b.z); pk.us[7] = f2bf(b.w);
    *(uint4*)(whbp + (size_t)g * 8) = pk.u4;
}

// ---------------- k0b: base[b,e] = dec[b,:]·Ws[e,:] + bs + bh (+bc) ----------------
__global__ __launch_bounds__(256) void kBase(const float* __restrict__ dh,
                                             const float* __restrict__ Ws,
                                             const float* __restrict__ bs,
                                             const float* __restrict__ bh,
                                             const float* __restrict__ bc,
                                             const int* __restrict__ uc,
                                             float* __restrict__ base) {
    __shared__ float dec[8][DIM];
    int ec = blockIdx.x >> 2;
    int bg = blockIdx.x & 3;
    int b0 = bg * 8, e0 = ec * 32;
    int tid = threadIdx.x;
    for (int i = tid; i < 8 * DIM; i += 256) {
        int bb = i >> 10, d = i & 1023;
        float vdec = (d < 512) ? dh[(b0 + bb) * 512 + d]
                               : dh[BATCH * 512 + (b0 + bb) * 512 + d - 512];
        dec[bb][d] = vdec;
    }
    __syncthreads();
    int el = tid >> 3, ds = tid & 7;
    int e = e0 + el;
    float acc[8] = {0.f, 0.f, 0.f, 0.f, 0.f, 0.f, 0.f, 0.f};
    const float* wrow = Ws + (size_t)e * DIM;
    for (int i = 0; i < 128; ++i) {
        int d = i * 8 + ds;
        float wv = wrow[d];
#pragma unroll
        for (int bb = 0; bb < 8; ++bb) acc[bb] += wv * dec[bb][d];
    }
#pragma unroll
    for (int bb = 0; bb < 8; ++bb) {
        float s = acc[bb];
        s += __shfl_xor(s, 1); s += __shfl_xor(s, 2); s += __shfl_xor(s, 4);
        acc[bb] = s;
    }
    if (ds == 0) {
        float bias = bs[e] + bh[e] + ((*uc) ? bc[e] : 0.0f);
#pragma unroll
        for (int bb = 0; bb < 8; ++bb) base[(b0 + bb) * DIM + e] = acc[bb] + bias;
    }
}

// ---------------- k2: fused GEMM(bf16 MFMA) + tanh + v-dot -> partial score ----------------
// 256-thread blocks (4 waves), tile M=64 x N=256 (quarter nq), BK=64.
// A staged f32->bf16 in LDS (dbuf, 144B stride: conflict-free); B direct global->reg
// from packed fragment layout (L2-resident). 4 blocks/CU resident -> barrier overlap via TLP.
// XCD grouping: block b -> XCD (b&7); strip = (b&7)*128 + (b>>3)/4, nq = (b>>3)&3:
// the 4 nq-blocks of a strip are consecutive on one XCD -> A re-reads hit that XCD's L2.
__global__ __launch_bounds__(256, 4) void kScore(const float* __restrict__ enc,
                                                 const ushort* __restrict__ whbp,
                                                 const float* __restrict__ base,
                                                 const float* __restrict__ pc,
                                                 const float* __restrict__ Wc,
                                                 const float* __restrict__ vv,
                                                 const int* __restrict__ uc,
                                                 float* __restrict__ scorep) {
    __shared__ ushort Al[2][64 * 72];   // 64 rows x 64 k, stride 72 ushorts (144B)
    __shared__ float pcl[64];
    __shared__ float red[4][64];

    const int tid = threadIdx.x;
    const int w = tid >> 6;             // wave 0..3 = wn (e-col group)
    const int lane = tid & 63;
    const int q = lane >> 4, l15 = lane & 15;

    const int c = blockIdx.x & 7;       // physical XCD (round-robin dispatch)
    const int j = blockIdx.x >> 3;      // position within XCD queue [0,512)
    const int strip = c * 128 + (j >> 2);
    const int nq = j & 3;
    const int b = strip >> 5;
    const int s0 = (strip & 31) << 6;

    const float* Ab = enc + ((size_t)(b * SEQ + s0)) * DIM;
    if (tid < 64) pcl[tid] = pc[b * SEQ + s0 + tid];

    // A staging map: thread -> row r, k-chunk kc (16 consecutive f32 = 64B)
    const int r = tid & 63, kc = tid >> 6;
    const float* agp = Ab + (size_t)r * DIM + (kc << 4);
    const int awoff = r * 72 + (kc << 4);

    // B fragments: eb = nq*16 + w*4 + ef; frag stride 32*512 ushorts = 1<<14
    const ushort* bgp = whbp + ((size_t)((nq << 4) + (w << 2)) << 14) + (lane << 3);

    f32x4 acc[4][4] = {};

    // prologue: stage kt = 0 into buf 0
    {
        float4 v0 = *(const float4*)agp;
        float4 v1 = *(const float4*)(agp + 4);
        float4 v2 = *(const float4*)(agp + 8);
        float4 v3 = *(const float4*)(agp + 12);
        union { ushort us[8]; uint4 u4; } p0, p1;
        p0.us[0] = f2bf(v0.x); p0.us[1] = f2bf(v0.y); p0.us[2] = f2bf(v0.z); p0.us[3] = f2bf(v0.w);
        p0.us[4] = f2bf(v1.x); p0.us[5] = f2bf(v1.y); p0.us[6] = f2bf(v1.z); p0.us[7] = f2bf(v1.w);
        p1.us[0] = f2bf(v2.x); p1.us[1] = f2bf(v2.y); p1.us[2] = f2bf(v2.z); p1.us[3] = f2bf(v2.w);
        p1.us[4] = f2bf(v3.x); p1.us[5] = f2bf(v3.y); p1.us[6] = f2bf(v3.z); p1.us[7] = f2bf(v3.w);
        *(uint4*)&Al[0][awoff] = p0.u4;
        *(uint4*)&Al[0][awoff + 8] = p1.u4;
    }
    __syncthreads();

    int buf = 0;
    for (int kt = 0; kt < 16; ++kt) {
        float4 v0, v1, v2, v3;
        if (kt < 15) {   // prefetch next A slice (HBM latency hides under MFMA phase)
            const float* p = agp + (kt + 1) * 64;
            v0 = *(const float4*)p;       v1 = *(const float4*)(p + 4);
            v2 = *(const float4*)(p + 8); v3 = *(const float4*)(p + 12);
        }
#pragma unroll
        for (int kb = 0; kb < 2; ++kb) {
            short8 bf[4], af[4];
#pragma unroll
            for (int ef = 0; ef < 4; ++ef)
                bf[ef] = *(const short8*)(bgp + ((size_t)ef << 14) + ((size_t)((kt << 1) + kb) << 9));
#pragma unroll
            for (int mf = 0; mf < 4; ++mf)
                af[mf] = *(const short8*)&Al[buf][((mf << 4) + l15) * 72 + (kb << 5) + (q << 3)];
#pragma unroll
            for (int ef = 0; ef < 4; ++ef)
#pragma unroll
                for (int mf = 0; mf < 4; ++mf)
                    acc[mf][ef] = __builtin_amdgcn_mfma_f32_16x16x32_bf16(af[mf], bf[ef], acc[mf][ef], 0, 0, 0);
        }
        if (kt < 15) {
            union { ushort us[8]; uint4 u4; } p0, p1;
            p0.us[0] = f2bf(v0.x); p0.us[1] = f2bf(v0.y); p0.us[2] = f2bf(v0.z); p0.us[3] = f2bf(v0.w);
            p0.us[4] = f2bf(v1.x); p0.us[5] = f2bf(v1.y); p0.us[6] = f2bf(v1.z); p0.us[7] = f2bf(v1.w);
            p1.us[0] = f2bf(v2.x); p1.us[1] = f2bf(v2.y); p1.us[2] = f2bf(v2.z); p1.us[3] = f2bf(v2.w);
            p1.us[4] = f2bf(v3.x); p1.us[5] = f2bf(v3.y); p1.us[6] = f2bf(v3.z); p1.us[7] = f2bf(v3.w);
            *(uint4*)&Al[buf ^ 1][awoff] = p0.u4;
            *(uint4*)&Al[buf ^ 1][awoff + 8] = p1.u4;
        }
        __syncthreads();
        buf ^= 1;
    }

    // epilogue: partial score = sum over this block's 256 e of tanh(acc+base+pc*Wc)*v
    const float ucf = (float)(*uc);
    float basee[4], ve[4], wce[4];
#pragma unroll
    for (int ef = 0; ef < 4; ++ef) {
        int e = (nq << 8) + (w << 6) + (ef << 4) + l15;
        basee[ef] = base[b * DIM + e];
        ve[ef] = vv[e];
        wce[ef] = Wc[e] * ucf;
    }
#pragma unroll
    for (int mf = 0; mf < 4; ++mf) {
#pragma unroll
        for (int rr = 0; rr < 4; ++rr) {
            int rl = (mf << 4) + (q << 2) + rr;   // row within the 64-row strip
            float p = pcl[rl];
            float sp = 0.f;
#pragma unroll
            for (int ef = 0; ef < 4; ++ef) {
                float x = acc[mf][ef][rr] + basee[ef] + p * wce[ef];
                float t = 1.0f - 2.0f / (1.0f + __expf(2.0f * x));  // tanh
                sp += t * ve[ef];
            }
            sp += __shfl_xor(sp, 1);
            sp += __shfl_xor(sp, 2);
            sp += __shfl_xor(sp, 4);
            sp += __shfl_xor(sp, 8);
            if (l15 == 0) red[w][rl] = sp;
        }
    }
    __syncthreads();
    if (tid < 64) {
        float s = red[0][tid] + red[1][tid] + red[2][tid] + red[3][tid];
        scorep[nq * (BATCH * SEQ) + b * SEQ + s0 + tid] = s;  // bv dropped (softmax-invariant)
    }
}

// ---------------- k3: softmax (sum of 4 partials) + mask + renorm + coverage ----------------
__global__ __launch_bounds__(512) void kSoftmax(const float* __restrict__ scorep,
                                                const float* __restrict__ mask,
                                                const float* __restrict__ pc,
                                                float* __restrict__ att,
                                                float* __restrict__ cov,
                                                int write_cov) {
    __shared__ float rmax[8], rsum[8];
    const int BS = BATCH * SEQ;
    int b = blockIdx.x, tid = threadIdx.x;
    int wv = tid >> 6, ln = tid & 63;
    float x[4];
#pragma unroll
    for (int i = 0; i < 4; ++i) {
        int idx = b * SEQ + tid + i * 512;
        x[i] = (scorep[idx] + scorep[BS + idx]) + (scorep[2 * BS + idx] + scorep[3 * BS + idx]);
    }
    float m = fmaxf(fmaxf(x[0], x[1]), fmaxf(x[2], x[3]));
#pragma unroll
    for (int o = 1; o < 64; o <<= 1) m = fmaxf(m, __shfl_xor(m, o));
    if (ln == 0) rmax[wv] = m;
    __syncthreads();
    m = rmax[0];
#pragma unroll
    for (int i = 1; i < 8; ++i) m = fmaxf(m, rmax[i]);

    float ms[4], wm[4];
#pragma unroll
    for (int i = 0; i < 4; ++i) ms[i] = mask[b * SEQ + tid + i * 512];
    float s = 0.f;
#pragma unroll
    for (int i = 0; i < 4; ++i) { wm[i] = __expf(x[i] - m) * ms[i]; s += wm[i]; }
#pragma unroll
    for (int o = 1; o < 64; o <<= 1) s += __shfl_xor(s, o);
    if (ln == 0) rsum[wv] = s;
    __syncthreads();
    s = 0.f;
#pragma unroll
    for (int i = 0; i < 8; ++i) s += rsum[i];
    float inv = 1.0f / s;
#pragma unroll
    for (int i = 0; i < 4; ++i) {
        float wf = wm[i] * inv;
        att[b * SEQ + tid + i * 512] = wf;
        if (write_cov) cov[b * SEQ + tid + i * 512] = pc[b * SEQ + tid + i * 512] + wf;
    }
}

// ---------------- k4: context partials over s-chunks ----------------
__global__ __launch_bounds__(256) void kCtxPart(const float* __restrict__ enc,
                                                const float* __restrict__ att,
                                                float* __restrict__ part) {
    __shared__ float wl[64];
    int bx = blockIdx.x;           // 32 b x 32 s-chunks
    int b = bx >> 5, sc = bx & 31;
    int tid = threadIdx.x;
    if (tid < 64) wl[tid] = att[b * SEQ + sc * 64 + tid];
    __syncthreads();
    const float* basep = enc + ((size_t)(b * SEQ + sc * 64)) * DIM + tid * 4;
    float4 acc = {0.f, 0.f, 0.f, 0.f};
#pragma unroll 4
    for (int i = 0; i < 64; ++i) {
        float w = wl[i];
        float4 xv = *(const float4*)(basep + (size_t)i * DIM);
        acc.x += w * xv.x; acc.y += w * xv.y; acc.z += w * xv.z; acc.w += w * xv.w;
    }
    *(float4*)(part + (size_t)bx * DIM + tid * 4) = acc;
}

// ---------------- k5: deterministic reduce of partials ----------------
__global__ __launch_bounds__(256) void kCtxReduce(const float* __restrict__ part,
                                                  float* __restrict__ ctx) {
    int g = blockIdx.x * 256 + threadIdx.x;  // 32768
    int b = g >> 10, d = g & 1023;
    float s = 0.f;
#pragma unroll
    for (int i = 0; i < 32; ++i) s += part[((size_t)(b * 32 + i) << 10) + d];
    ctx[g] = s;
}

extern "C" void kernel_launch(void* const* d_in, const int* in_sizes, int n_in,
                              void* d_out, int out_size, void* d_ws, size_t ws_size,
                              hipStream_t stream) {
    const float* dh   = (const float*)d_in[0];
    const float* enc  = (const float*)d_in[1];
    const float* mask = (const float*)d_in[2];
    const float* pc   = (const float*)d_in[3];
    const float* Wh   = (const float*)d_in[4];
    const float* bh   = (const float*)d_in[5];
    const float* Ws   = (const float*)d_in[6];
    const float* bs   = (const float*)d_in[7];
    const float* Wc   = (const float*)d_in[8];
    const float* bc   = (const float*)d_in[9];
    const float* vv   = (const float*)d_in[10];
    // d_in[11] = bv: uniform shift of scores -> softmax-invariant -> unused
    const int* uc     = (const int*)d_in[12];

    float* ctx = (float*)d_out;
    float* att = ctx + BATCH * DIM;
    float* cov = att + BATCH * SEQ;
    int write_cov = (out_size >= BATCH * (DIM + 2 * SEQ)) ? 1 : 0;

    ushort* whbp  = (ushort*)d_ws;                                  // 2 MB (packed)
    float* base   = (float*)((char*)d_ws + 2u * 1024u * 1024u);     // 128 KB
    float* scorep = base + BATCH * DIM;                             // 1 MB (4 quarters)
    float* part   = scorep + 4 * BATCH * SEQ;                       // 4 MB

    kWhPack<<<512, 256, 0, stream>>>(Wh, whbp);
    kBase<<<128, 256, 0, stream>>>(dh, Ws, bs, bh, bc, uc, base);
    kScore<<<4096, 256, 0, stream>>>(enc, whbp, base, pc, Wc, vv, uc, scorep);
    kSoftmax<<<BATCH, 512, 0, stream>>>(scorep, mask, pc, att, cov, write_cov);
    kCtxPart<<<1024, 256, 0, stream>>>(enc, att, part);
    kCtxReduce<<<128, 256, 0, stream>>>(part, ctx);
}

// Round 6
// 289.950 us; speedup vs baseline: 1.0302x; 1.0302x over previous
//
#include <hip/hip_runtime.h>
#include <hip/hip_bf16.h>

#define BATCH 32
#define SEQ   2048
#define DIM   1024

typedef __attribute__((ext_vector_type(4))) float f32x4;
typedef __attribute__((ext_vector_type(8))) short short8;

static __device__ __forceinline__ ushort f2bf(float x) {
    __hip_bfloat16 h = __float2bfloat16(x);
    union { __hip_bfloat16 h; ushort u; } cv; cv.h = h;
    return cv.u;
}

// async global -> LDS, 16B per lane. LDS dest = wave-uniform base (HW adds lane*16).
static __device__ __forceinline__ void gll16(const void* g, void* l) {
    __builtin_amdgcn_global_load_lds(
        (const __attribute__((address_space(1))) void*)g,
        (__attribute__((address_space(3))) void*)l, 16, 0, 0);
}

// ---------------- k0a: Wh f32 -> bf16, packed in MFMA B-fragment order ----------------
// whbp[((eb*32 + kb)*64 + lane)*8 + j] = bf16( Wh[eb*16 + (lane&15)][kb*32 + (lane>>4)*8 + j] )
__global__ __launch_bounds__(256) void kWhPack(const float* __restrict__ Wh,
                                               ushort* __restrict__ whbp) {
    int g = blockIdx.x * 256 + threadIdx.x;      // 131072 total
    int l  = g & 63;
    int kb = (g >> 6) & 31;
    int eb = g >> 11;
    int e  = eb * 16 + (l & 15);
    int k0 = kb * 32 + (l >> 4) * 8;
    const float* src = Wh + (size_t)e * DIM + k0;
    float4 a = *(const float4*)src;
    float4 b = *(const float4*)(src + 4);
    union { ushort us[8]; uint4 u4; } pk;
    pk.us[0] = f2bf(a.x); pk.us[1] = f2bf(a.y); pk.us[2] = f2bf(a.z); pk.us[3] = f2bf(a.w);
    pk.us[4] = f2bf(b.x); pk.us[5] = f2bf(b.y); pk.us[6] = f2bf(b.z); pk.us[7] = f2bf(b.w);
    *(uint4*)(whbp + (size_t)g * 8) = pk.u4;
}

// ---------------- k0b: base[b,e] = dec[b,:]·Ws[e,:] + bs + bh (+bc) ----------------
__global__ __launch_bounds__(256) void kBase(const float* __restrict__ dh,
                                             const float* __restrict__ Ws,
                                             const float* __restrict__ bs,
                                             const float* __restrict__ bh,
                                             const float* __restrict__ bc,
                                             const int* __restrict__ uc,
                                             float* __restrict__ base) {
    __shared__ float dec[8][DIM];
    int ec = blockIdx.x >> 2;
    int bg = blockIdx.x & 3;
    int b0 = bg * 8, e0 = ec * 32;
    int tid = threadIdx.x;
    for (int i = tid; i < 8 * DIM; i += 256) {
        int bb = i >> 10, d = i & 1023;
        float vdec = (d < 512) ? dh[(b0 + bb) * 512 + d]
                               : dh[BATCH * 512 + (b0 + bb) * 512 + d - 512];
        dec[bb][d] = vdec;
    }
    __syncthreads();
    int el = tid >> 3, ds = tid & 7;
    int e = e0 + el;
    float acc[8] = {0.f, 0.f, 0.f, 0.f, 0.f, 0.f, 0.f, 0.f};
    const float* wrow = Ws + (size_t)e * DIM;
    for (int i = 0; i < 128; ++i) {
        int d = i * 8 + ds;
        float wv = wrow[d];
#pragma unroll
        for (int bb = 0; bb < 8; ++bb) acc[bb] += wv * dec[bb][d];
    }
#pragma unroll
    for (int bb = 0; bb < 8; ++bb) {
        float s = acc[bb];
        s += __shfl_xor(s, 1); s += __shfl_xor(s, 2); s += __shfl_xor(s, 4);
        acc[bb] = s;
    }
    if (ds == 0) {
        float bias = bs[e] + bh[e] + ((*uc) ? bc[e] : 0.0f);
#pragma unroll
        for (int bb = 0; bb < 8; ++bb) base[(b0 + bb) * DIM + e] = acc[bb] + bias;
    }
}

// ---------------- k2: pipelined fused GEMM + tanh + v-dot -> partial score ----------------
// BM=256 x BN=256 (nb quarter), BK=64, 512 thr = 8 waves (2 wm x 4 wn), wave tile 128x64.
// A and B both held in LDS in MFMA-fragment-linear order (lane*16B) -> all DS ops conflict-free.
// B staged via global_load_lds from packed whbp; A reg-staged (f32->bf16) one tile ahead.
// Counted vmcnt(8) at the per-tile barrier: next tile's loads stay in flight (T3+T4).
__global__ __launch_bounds__(512, 2) void kScore(const float* __restrict__ enc,
                                                 const ushort* __restrict__ whbp,
                                                 const float* __restrict__ base,
                                                 const float* __restrict__ pc,
                                                 const float* __restrict__ Wc,
                                                 const float* __restrict__ vv,
                                                 const int* __restrict__ uc,
                                                 float* __restrict__ scorep) {
    __shared__ ushort Al[2][16384];   // 32KB per buf: 32 frags (16 mt x 2 kb) x 1KB
    __shared__ ushort Bl[2][16384];   // 32KB per buf: 32 frags (16 eb x 2 kb) x 1KB
    __shared__ float pcl[256];
    __shared__ float red[4][256];

    const int tid = threadIdx.x;
    const int w = tid >> 6, lane = tid & 63;
    const int q = lane >> 4, l15 = lane & 15;
    const int wm = w >> 2, wn = w & 3;

    // XCD grouping: xcd x gets m-strips [x*32,(x+1)*32), the 4 nb of a strip adjacent in time.
    const int x = blockIdx.x & 7;
    const int j = blockIdx.x >> 3;              // [0,128)
    const int ms = x * 32 + (j >> 2);           // m-strip [0,256)
    const int nb = j & 3;
    const int b = ms >> 3;
    const int s0 = (ms & 7) << 8;               // 256-row strip within batch b

    const float* Ab = enc + ((size_t)(b * SEQ + s0)) * DIM;
    if (tid < 256) pcl[tid] = pc[b * SEQ + s0 + tid];

    // A staging map: thread covers 4 fragment-lane slots (i=0..3): frag fA=i*8+w, lane.
    const float* agp[4];
    int adst[4];
#pragma unroll
    for (int i = 0; i < 4; ++i) {
        int fA = i * 8 + w, mt = fA >> 1, kb = fA & 1;
        int row = mt * 16 + l15, kk = kb * 32 + q * 8;
        agp[i] = Ab + (size_t)row * DIM + kk;
        adst[i] = fA * 512 + lane * 8;          // ushort idx
    }
    // B staging map: per call c, wave stages frag fB=c*8+w via gll16 (src is per-lane).
    const ushort* bsrc[4];
    int bdst[4];
#pragma unroll
    for (int c = 0; c < 4; ++c) {
        int fB = c * 8 + w, ebl = fB >> 1, kbit = fB & 1;
        bsrc[c] = whbp + ((size_t)((nb * 16 + ebl) * 32 + kbit)) * 512 + lane * 8;
        bdst[c] = fB * 512;
    }

    f32x4 acc[8][4] = {};
    float4 rA[8];

#define CVT_WRITE(BUF) do { \
    _Pragma("unroll") \
    for (int i = 0; i < 4; ++i) { \
        union { ushort us[8]; uint4 u4; } pk_; \
        float4 lo = rA[2*i], hi = rA[2*i+1]; \
        pk_.us[0]=f2bf(lo.x); pk_.us[1]=f2bf(lo.y); pk_.us[2]=f2bf(lo.z); pk_.us[3]=f2bf(lo.w); \
        pk_.us[4]=f2bf(hi.x); pk_.us[5]=f2bf(hi.y); pk_.us[6]=f2bf(hi.z); pk_.us[7]=f2bf(hi.w); \
        *(uint4*)&Al[BUF][adst[i]] = pk_.u4; \
    } } while (0)

#define ALOAD(KT) do { \
    _Pragma("unroll") \
    for (int i = 0; i < 4; ++i) { \
        const float* p_ = agp[i] + (KT) * 64; \
        rA[2*i] = *(const float4*)p_; rA[2*i+1] = *(const float4*)(p_ + 4); \
    } } while (0)

#define GLLB(KT, BUF) do { \
    _Pragma("unroll") \
    for (int c = 0; c < 4; ++c) \
        gll16(bsrc[c] + (size_t)(KT) * 1024, &Bl[BUF][bdst[c]]); \
    } while (0)

#define MFMA_PHASE(BUF, KB) do { \
    short8 a_[8], b_[4]; \
    _Pragma("unroll") \
    for (int mf = 0; mf < 8; ++mf) \
        a_[mf] = *(const short8*)&Al[BUF][(((wm<<3)+mf)*2+(KB))*512 + (lane<<3)]; \
    _Pragma("unroll") \
    for (int ef = 0; ef < 4; ++ef) \
        b_[ef] = *(const short8*)&Bl[BUF][(((wn<<2)+ef)*2+(KB))*512 + (lane<<3)]; \
    __builtin_amdgcn_s_setprio(1); \
    _Pragma("unroll") \
    for (int ef = 0; ef < 4; ++ef) \
        _Pragma("unroll") \
        for (int mf = 0; mf < 8; ++mf) \
            acc[mf][ef] = __builtin_amdgcn_mfma_f32_16x16x32_bf16(a_[mf], b_[ef], acc[mf][ef], 0, 0, 0); \
    __builtin_amdgcn_s_setprio(0); \
    } while (0)

    // ---- prologue ----
    ALOAD(0);              // Aload(0) (oldest in vmcnt FIFO)
    GLLB(0, 0);            // gllB(0)
    CVT_WRITE(0);          // consumes rA(0): auto-wait vmcnt(4), gllB(0) stays in flight
    ALOAD(1);              // Aload(1)
    __syncthreads();       // full drain (prologue only): A0+B0 ready in LDS
    GLLB(1, 1);            // gllB(1) in flight across iter 0

    // ---- main loop: tile kt in LDS[kt&1]; rA holds A(kt+1); gllB(kt+1) in flight ----
    for (int kt = 0; kt < 16; ++kt) {
        const int cur = kt & 1, nxt = cur ^ 1;
        MFMA_PHASE(cur, 0);
        if (kt < 15) {
            CVT_WRITE(nxt);            // A(kt+1) -> LDS[nxt]; auto-wait leaves gllB(kt+1) in flight
            if (kt < 14) ALOAD(kt + 2);
        }
        MFMA_PHASE(cur, 1);
        if (kt < 15) {
            asm volatile("s_waitcnt lgkmcnt(0)" ::: "memory");     // A ds_writes visible
            if (kt < 14) { asm volatile("s_waitcnt vmcnt(8)" ::: "memory"); }  // gllB(kt+1) landed; Aload(kt+2) stays
            else         { asm volatile("s_waitcnt vmcnt(0)" ::: "memory"); }
            __builtin_amdgcn_sched_barrier(0);
            __builtin_amdgcn_s_barrier();
            __builtin_amdgcn_sched_barrier(0);
            if (kt < 14) GLLB(kt + 2, cur);   // overwrite cur (all waves past their reads)
        }
    }

    // ---- epilogue: partial score over this block's 256 e ----
    const float ucf = (float)(*uc);
    float basee[4], ve[4], wce[4];
#pragma unroll
    for (int ef = 0; ef < 4; ++ef) {
        int e = (nb << 8) + ((wn << 2) + ef) * 16 + l15;
        basee[ef] = base[b * DIM + e];
        ve[ef] = vv[e];
        wce[ef] = Wc[e] * ucf;
    }
#pragma unroll
    for (int mf = 0; mf < 8; ++mf) {
#pragma unroll
        for (int r = 0; r < 4; ++r) {
            int rl = (wm << 7) + (mf << 4) + (q << 2) + r;   // row in [0,256)
            float p = pcl[rl];
            float sp = 0.f;
#pragma unroll
            for (int ef = 0; ef < 4; ++ef) {
                float xv = acc[mf][ef][r] + basee[ef] + p * wce[ef];
                float t = 1.0f - 2.0f / (1.0f + __expf(2.0f * xv));  // tanh
                sp += t * ve[ef];
            }
            sp += __shfl_xor(sp, 1);
            sp += __shfl_xor(sp, 2);
            sp += __shfl_xor(sp, 4);
            sp += __shfl_xor(sp, 8);
            if (l15 == 0) red[wn][rl] = sp;
        }
    }
    __syncthreads();
    if (tid < 256) {
        float s = (red[0][tid] + red[1][tid]) + (red[2][tid] + red[3][tid]);
        scorep[nb * (BATCH * SEQ) + b * SEQ + s0 + tid] = s;  // bv dropped (softmax-invariant)
    }
}

// ---------------- k3: softmax (sum of 4 partials) + mask + renorm + coverage ----------------
__global__ __launch_bounds__(512) void kSoftmax(const float* __restrict__ scorep,
                                                const float* __restrict__ mask,
                                                const float* __restrict__ pc,
                                                float* __restrict__ att,
                                                float* __restrict__ cov,
                                                int write_cov) {
    __shared__ float rmax[8], rsum[8];
    const int BS = BATCH * SEQ;
    int b = blockIdx.x, tid = threadIdx.x;
    int wv = tid >> 6, ln = tid & 63;
    float x[4];
#pragma unroll
    for (int i = 0; i < 4; ++i) {
        int idx = b * SEQ + tid + i * 512;
        x[i] = (scorep[idx] + scorep[BS + idx]) + (scorep[2 * BS + idx] + scorep[3 * BS + idx]);
    }
    float m = fmaxf(fmaxf(x[0], x[1]), fmaxf(x[2], x[3]));
#pragma unroll
    for (int o = 1; o < 64; o <<= 1) m = fmaxf(m, __shfl_xor(m, o));
    if (ln == 0) rmax[wv] = m;
    __syncthreads();
    m = rmax[0];
#pragma unroll
    for (int i = 1; i < 8; ++i) m = fmaxf(m, rmax[i]);

    float ms[4], wm[4];
#pragma unroll
    for (int i = 0; i < 4; ++i) ms[i] = mask[b * SEQ + tid + i * 512];
    float s = 0.f;
#pragma unroll
    for (int i = 0; i < 4; ++i) { wm[i] = __expf(x[i] - m) * ms[i]; s += wm[i]; }
#pragma unroll
    for (int o = 1; o < 64; o <<= 1) s += __shfl_xor(s, o);
    if (ln == 0) rsum[wv] = s;
    __syncthreads();
    s = 0.f;
#pragma unroll
    for (int i = 0; i < 8; ++i) s += rsum[i];
    float inv = 1.0f / s;
#pragma unroll
    for (int i = 0; i < 4; ++i) {
        float wf = wm[i] * inv;
        att[b * SEQ + tid + i * 512] = wf;
        if (write_cov) cov[b * SEQ + tid + i * 512] = pc[b * SEQ + tid + i * 512] + wf;
    }
}

// ---------------- k4: context partials over s-chunks ----------------
__global__ __launch_bounds__(256) void kCtxPart(const float* __restrict__ enc,
                                                const float* __restrict__ att,
                                                float* __restrict__ part) {
    __shared__ float wl[64];
    int bx = blockIdx.x;           // 32 b x 32 s-chunks
    int b = bx >> 5, sc = bx & 31;
    int tid = threadIdx.x;
    if (tid < 64) wl[tid] = att[b * SEQ + sc * 64 + tid];
    __syncthreads();
    const float* basep = enc + ((size_t)(b * SEQ + sc * 64)) * DIM + tid * 4;
    float4 acc = {0.f, 0.f, 0.f, 0.f};
#pragma unroll 4
    for (int i = 0; i < 64; ++i) {
        float w = wl[i];
        float4 xv = *(const float4*)(basep + (size_t)i * DIM);
        acc.x += w * xv.x; acc.y += w * xv.y; acc.z += w * xv.z; acc.w += w * xv.w;
    }
    *(float4*)(part + (size_t)bx * DIM + tid * 4) = acc;
}

// ---------------- k5: deterministic reduce of partials ----------------
__global__ __launch_bounds__(256) void kCtxReduce(const float* __restrict__ part,
                                                  float* __restrict__ ctx) {
    int g = blockIdx.x * 256 + threadIdx.x;  // 32768
    int b = g >> 10, d = g & 1023;
    float s = 0.f;
#pragma unroll
    for (int i = 0; i < 32; ++i) s += part[((size_t)(b * 32 + i) << 10) + d];
    ctx[g] = s;
}

extern "C" void kernel_launch(void* const* d_in, const int* in_sizes, int n_in,
                              void* d_out, int out_size, void* d_ws, size_t ws_size,
                              hipStream_t stream) {
    const float* dh   = (const float*)d_in[0];
    const float* enc  = (const float*)d_in[1];
    const float* mask = (const float*)d_in[2];
    const float* pc   = (const float*)d_in[3];
    const float* Wh   = (const float*)d_in[4];
    const float* bh   = (const float*)d_in[5];
    const float* Ws   = (const float*)d_in[6];
    const float* bs   = (const float*)d_in[7];
    const float* Wc   = (const float*)d_in[8];
    const float* bc   = (const float*)d_in[9];
    const float* vv   = (const float*)d_in[10];
    // d_in[11] = bv: uniform shift of scores -> softmax-invariant -> unused
    const int* uc     = (const int*)d_in[12];

    float* ctx = (float*)d_out;
    float* att = ctx + BATCH * DIM;
    float* cov = att + BATCH * SEQ;
    int write_cov = (out_size >= BATCH * (DIM + 2 * SEQ)) ? 1 : 0;

    ushort* whbp  = (ushort*)d_ws;                                  // 2 MB (packed)
    float* base   = (float*)((char*)d_ws + 2u * 1024u * 1024u);     // 128 KB
    float* scorep = base + BATCH * DIM;                             // 1 MB (4 quarters)
    float* part   = scorep + 4 * BATCH * SEQ;                       // 4 MB

    kWhPack<<<512, 256, 0, stream>>>(Wh, whbp);
    kBase<<<128, 256, 0, stream>>>(dh, Ws, bs, bh, bc, uc, base);
    kScore<<<1024, 512, 0, stream>>>(enc, whbp, base, pc, Wc, vv, uc, scorep);
    kSoftmax<<<BATCH, 512, 0, stream>>>(scorep, mask, pc, att, cov, write_cov);
    kCtxPart<<<1024, 256, 0, stream>>>(enc, att, part);
    kCtxReduce<<<128, 256, 0, stream>>>(part, ctx);
}